// Round 6
// baseline (135.517 us; speedup 1.0000x reference)
//
#include <hip/hip_runtime.h>
#include <stdint.h>

#define NB 32
#define NA 48
#define HIN 64
#define EIN 32
#define HH 64
#define HG 16
#define NCELLS 5
#define GH 1024        // HG*HH
#define EROW 40        // shorts per staged E row (32 + 8 pad; 80 B, 16B-aligned rows)

typedef __attribute__((ext_vector_type(8))) short short8;   // 8 x bf16 (4 VGPRs)
typedef __attribute__((ext_vector_type(4))) float float4v;  // 4 x f32

__device__ __forceinline__ unsigned short f2bf(float f) {
    union { float f; unsigned int u; } v; v.f = f;
    unsigned int u = v.u + 0x7FFF + ((v.u >> 16) & 1);      // round-to-nearest-even
    return (unsigned short)(u >> 16);
}
__device__ __forceinline__ float bf2f(unsigned short s) {
    union { unsigned int u; float f; } v; v.u = ((unsigned int)s) << 16;
    return v.f;
}

// One-shot: W_e [32,1024] fp32 -> split bf16 (hi + lo) in MFMA B-fragment layout.
// slot o = ct*512 + l*8 + jj holds W_e[(l>>4)*8 + jj][ct*16 + (l&15)]
__global__ __launch_bounds__(256) void swizzle_We(const float* __restrict__ W_e,
                                                  unsigned short* __restrict__ hiB,
                                                  unsigned short* __restrict__ loB) {
    const int o  = blockIdx.x * 256 + threadIdx.x;   // 0..32767
    const int ct = o >> 9;
    const int l  = (o >> 3) & 63;
    const int jj = o & 7;
    const int k  = (l >> 4) * 8 + jj;
    const int c  = ct * 16 + (l & 15);
    const float x = W_e[k * GH + c];
    const unsigned short hb = f2bf(x);
    hiB[o] = hb;
    loB[o] = f2bf(x - bf2f(hb));
}

// Edge phase specialized on compile-time tile count NT (0..3): every fragment/
// mask array constant-indexed -> register-resident (round-4 runtime-indexed
// version spilled to scratch: VALUBusy 57%, MfmaUtil 0.7%).
template <int NT>
__device__ __forceinline__ void edge_phase(
    const unsigned short* __restrict__ hiB, const unsigned short* __restrict__ loB,
    const float* __restrict__ b_e,
    const unsigned short* EcolH, const unsigned short* EcolL,
    const int* ilist, int cnt, int wave, int lane, int mrow, int quad,
    float* Esum_s)
{
    const float4v zero4 = {0.0f, 0.0f, 0.0f, 0.0f};
    short8 aH[NT ? NT : 1], aL[NT ? NT : 1];
    float4v mk[NT ? NT : 1];
    #pragma unroll
    for (int rt = 0; rt < NT; ++rt) {
        const int i = ilist[16 * rt + mrow];
        aH[rt] = *(const short8*)(&EcolH[i * EROW + quad * 8]);
        aL[rt] = *(const short8*)(&EcolL[i * EROW + quad * 8]);
        #pragma unroll
        for (int rg = 0; rg < 4; ++rg)
            mk[rt][rg] = (16 * rt + quad * 4 + rg < cnt) ? 1.0f : 0.0f;
    }
    float be[16];
    #pragma unroll
    for (int t = 0; t < 16; ++t)
        be[t] = b_e[(wave * 16 + t) * 16 + mrow];

    #pragma unroll 4
    for (int t = 0; t < 16; ++t) {
        const int ct = wave * 16 + t;
        const short8 bfH = *(const short8*)(hiB + (size_t)ct * 512 + lane * 8);
        const short8 bfL = *(const short8*)(loB + (size_t)ct * 512 + lane * 8);
        float psum = 0.0f;
        #pragma unroll
        for (int rt = 0; rt < NT; ++rt) {
            // split-bf16 product: A_lo*B_hi + A_hi*B_lo + A_hi*B_hi (fp32 acc)
            float4v d = __builtin_amdgcn_mfma_f32_16x16x32_bf16(aL[rt], bfH, zero4, 0, 0, 0);
            d = __builtin_amdgcn_mfma_f32_16x16x32_bf16(aH[rt], bfL, d, 0, 0, 0);
            d = __builtin_amdgcn_mfma_f32_16x16x32_bf16(aH[rt], bfH, d, 0, 0, 0);
            #pragma unroll
            for (int rg = 0; rg < 4; ++rg)
                psum = fmaf(fmaxf(d[rg] + be[t], 0.0f), mk[rt][rg], psum);
        }
        psum += __shfl_xor(psum, 16);
        psum += __shfl_xor(psum, 32);
        if (lane < 16) {
            const int c = ct * 16 + lane;
            Esum_s[(c >> 6) * 68 + (c & 63)] = psum;
        }
    }
}

// One block per node (b,j), 256 threads / 4 waves.
// __launch_bounds__(256, 2): 2 waves/EU -> VGPR cap 256 so the 80-float
// gate-weight arrays stay register-resident (round 5's default alloc was 72
// VGPRs -> spilled weights to scratch; VALUBusy 16%, 60 us).
__global__ __launch_bounds__(256, 2) void fused_kernel(
    const float* __restrict__ A,  const float* __restrict__ h,
    const float* __restrict__ E,
    const float* __restrict__ W_h, const float* __restrict__ b_h,
    const float* __restrict__ b_e,
    const float* __restrict__ W_ih, const float* __restrict__ b_ih,
    const float* __restrict__ W_hh, const float* __restrict__ b_hh,
    const unsigned short* __restrict__ hiB, const unsigned short* __restrict__ loB,
    float* __restrict__ out)
{
    __shared__ unsigned short EcolH[NA * EROW];  // E[b,:,j,:] bf16 hi
    __shared__ unsigned short EcolL[NA * EROW];  // bf16 lo (residual)
    __shared__ float Esum_s[16 * 68];            // padded stride 68 (conflict-free)
    __shared__ int   ilist[NA];
    __shared__ int   cnt_s;
    __shared__ float hc_s[HH];
    __shared__ float M_s[HG];
    __shared__ float gsum_s[2 * HH];
    __shared__ float gin_s[HH], ghn_s[HH];

    const int node = blockIdx.x;                // b*48 + j
    const int b = node / NA, j = node - b * NA;
    const int tid = threadIdx.x, lane = tid & 63, wave = tid >> 6;
    const int mrow = lane & 15, quad = lane >> 4;

    // ---- stage E[b,:,j,:] -> split bf16 LDS (coalesced float4 per 8 threads/row) ----
    for (int idx = tid; idx < NA * 8; idx += 256) {
        const int r = idx >> 3, q = idx & 7;
        const float4 ev = *(const float4*)(E + ((size_t)(b * NA + r) * NA + j) * EIN + 4 * q);
        unsigned short h0 = f2bf(ev.x), h1 = f2bf(ev.y), h2 = f2bf(ev.z), h3 = f2bf(ev.w);
        unsigned short l0 = f2bf(ev.x - bf2f(h0)), l1 = f2bf(ev.y - bf2f(h1));
        unsigned short l2 = f2bf(ev.z - bf2f(h2)), l3 = f2bf(ev.w - bf2f(h3));
        *(uint2*)(&EcolH[r * EROW + 4 * q]) =
            make_uint2((unsigned int)h0 | ((unsigned int)h1 << 16),
                       (unsigned int)h2 | ((unsigned int)h3 << 16));
        *(uint2*)(&EcolL[r * EROW + 4 * q]) =
            make_uint2((unsigned int)l0 | ((unsigned int)l1 << 16),
                       (unsigned int)l2 | ((unsigned int)l3 << 16));
    }
    // ---- compacted active-row list from column j of A (entries exactly 0/1) ----
    if (tid < 64) {
        if (tid < NA) ilist[tid] = 0;
        const float a = (tid < NA) ? A[((size_t)b * NA + tid) * NA + j] : 0.0f;
        const unsigned long long m = __ballot(a != 0.0f);
        if (a != 0.0f) ilist[__popcll(m & ((1ull << tid) - 1ull))] = tid;
        if (tid == 0) cnt_s = (int)__popcll(m);
    }
    __syncthreads();

    const int cnt = cnt_s;   // block-uniform -> scalar branches below
    if (cnt == 0)
        edge_phase<0>(hiB, loB, b_e, EcolH, EcolL, ilist, cnt, wave, lane, mrow, quad, Esum_s);
    else if (cnt <= 16)
        edge_phase<1>(hiB, loB, b_e, EcolH, EcolL, ilist, cnt, wave, lane, mrow, quad, Esum_s);
    else if (cnt <= 32)
        edge_phase<2>(hiB, loB, b_e, EcolH, EcolL, ilist, cnt, wave, lane, mrow, quad, Esum_s);
    else
        edge_phase<3>(hiB, loB, b_e, EcolH, EcolL, ilist, cnt, wave, lane, mrow, quad, Esum_s);

    // ---- phase 2 setup: gate weights in registers (threads 0..191) ----
    float wih[HG], whh[HH];
    float bihc = 0.0f, bhhc = 0.0f;
    if (tid < 3 * HH) {
        #pragma unroll
        for (int g = 0; g < HG; g += 4) {
            const float4 v = *(const float4*)(W_ih + (size_t)tid * HG + g);
            wih[g] = v.x; wih[g + 1] = v.y; wih[g + 2] = v.z; wih[g + 3] = v.w;
        }
        #pragma unroll
        for (int k = 0; k < HH; k += 4) {
            const float4 v = *(const float4*)(W_hh + (size_t)tid * HH + k);
            whh[k] = v.x; whh[k + 1] = v.y; whh[k + 2] = v.z; whh[k + 3] = v.w;
        }
        bihc = b_ih[tid];
        bhhc = b_hh[tid];
    }
    // hv = relu(h @ W_h + b_h) * maskh  (wave 0; maskh from ROW j of A)
    if (tid < HH) {
        const float a = (lane < NA) ? A[(size_t)node * NA + lane] : 0.0f;
        const unsigned long long mrowm = __ballot(a != 0.0f);
        const float maskh = (mrowm != 0ull) ? 1.0f : 0.0f;
        const float hr = h[(size_t)node * HIN + lane];
        float acc = b_h[lane];
        #pragma unroll
        for (int k = 0; k < HIN; ++k)
            acc = fmaf(__shfl(hr, k), W_h[k * HH + lane], acc);
        hc_s[lane] = fmaxf(acc, 0.0f) * maskh;
    }
    __syncthreads();

    // ---- phase 2: 5 GRUCell iterations (no outer unroll: keep I-cache small) ----
    #pragma unroll 1
    for (int it = 0; it < NCELLS; ++it) {
        {   // M[g] = Esum[g,:] . hc  -- all 256 threads, stride-68 (conflict-free)
            const int g = tid >> 4, q = tid & 15;
            const float4v e4 = *(const float4v*)(Esum_s + g * 68 + 4 * q);
            const float4v h4 = *(const float4v*)(hc_s + 4 * q);
            float p = e4[0] * h4[0];
            p = fmaf(e4[1], h4[1], p);
            p = fmaf(e4[2], h4[2], p);
            p = fmaf(e4[3], h4[3], p);
            p += __shfl_xor(p, 1);
            p += __shfl_xor(p, 2);
            p += __shfl_xor(p, 4);
            p += __shfl_xor(p, 8);
            if (q == 0) M_s[g] = p;
        }
        __syncthreads();
        if (tid < 3 * HH) {   // gate pre-activations; multi-accumulator for ILP
            float gi0 = bihc, gi1 = 0.0f;
            #pragma unroll
            for (int g = 0; g < HG; g += 8) {
                const float4v m4a = *(const float4v*)(M_s + g);
                const float4v m4b = *(const float4v*)(M_s + g + 4);
                gi0 = fmaf(m4a[0], wih[g], gi0);
                gi1 = fmaf(m4a[1], wih[g + 1], gi1);
                gi0 = fmaf(m4a[2], wih[g + 2], gi0);
                gi1 = fmaf(m4a[3], wih[g + 3], gi1);
                gi0 = fmaf(m4b[0], wih[g + 4], gi0);
                gi1 = fmaf(m4b[1], wih[g + 5], gi1);
                gi0 = fmaf(m4b[2], wih[g + 6], gi0);
                gi1 = fmaf(m4b[3], wih[g + 7], gi1);
            }
            float gh0 = bhhc, gh1 = 0.0f, gh2 = 0.0f, gh3 = 0.0f;
            #pragma unroll
            for (int k = 0; k < HH; k += 16) {
                const float4v a4 = *(const float4v*)(hc_s + k);
                const float4v b4 = *(const float4v*)(hc_s + k + 4);
                const float4v c4 = *(const float4v*)(hc_s + k + 8);
                const float4v d4 = *(const float4v*)(hc_s + k + 12);
                gh0 = fmaf(a4[0], whh[k], gh0);      gh1 = fmaf(a4[1], whh[k + 1], gh1);
                gh2 = fmaf(a4[2], whh[k + 2], gh2);  gh3 = fmaf(a4[3], whh[k + 3], gh3);
                gh0 = fmaf(b4[0], whh[k + 4], gh0);  gh1 = fmaf(b4[1], whh[k + 5], gh1);
                gh2 = fmaf(b4[2], whh[k + 6], gh2);  gh3 = fmaf(b4[3], whh[k + 7], gh3);
                gh0 = fmaf(c4[0], whh[k + 8], gh0);  gh1 = fmaf(c4[1], whh[k + 9], gh1);
                gh2 = fmaf(c4[2], whh[k + 10], gh2); gh3 = fmaf(c4[3], whh[k + 11], gh3);
                gh0 = fmaf(d4[0], whh[k + 12], gh0); gh1 = fmaf(d4[1], whh[k + 13], gh1);
                gh2 = fmaf(d4[2], whh[k + 14], gh2); gh3 = fmaf(d4[3], whh[k + 15], gh3);
            }
            const float gi = gi0 + gi1;
            const float gh = (gh0 + gh1) + (gh2 + gh3);
            if (tid < 2 * HH) gsum_s[tid] = gi + gh;            // r,z need only the sum
            else { gin_s[tid - 2 * HH] = gi; ghn_s[tid - 2 * HH] = gh; }
        }
        __syncthreads();
        if (tid < HH) {
            const float r = 1.0f / (1.0f + __expf(-gsum_s[tid]));
            const float z = 1.0f / (1.0f + __expf(-gsum_s[HH + tid]));
            const float nin = gin_s[tid] + r * ghn_s[tid];
            const float n = 1.0f - 2.0f / (__expf(2.0f * nin) + 1.0f);  // tanh
            hc_s[tid] = (1.0f - z) * n + z * hc_s[tid];
        }
        __syncthreads();
    }

    if (tid < HH) out[(size_t)node * HH + tid] = hc_s[tid];
}

extern "C" void kernel_launch(void* const* d_in, const int* in_sizes, int n_in,
                              void* d_out, int out_size, void* d_ws, size_t ws_size,
                              hipStream_t stream) {
    const float* A    = (const float*)d_in[0];
    const float* h    = (const float*)d_in[1];
    const float* E    = (const float*)d_in[2];
    const float* W_h  = (const float*)d_in[3];
    const float* b_h  = (const float*)d_in[4];
    const float* W_e  = (const float*)d_in[5];
    const float* b_e  = (const float*)d_in[6];
    const float* W_ih = (const float*)d_in[7];
    const float* b_ih = (const float*)d_in[8];
    const float* W_hh = (const float*)d_in[9];
    const float* b_hh = (const float*)d_in[10];
    unsigned short* hiB = (unsigned short*)d_ws;            // 64 KB
    unsigned short* loB = hiB + 32768;                      // 64 KB
    float* out = (float*)d_out;

    hipLaunchKernelGGL(swizzle_We, dim3(128), dim3(256), 0, stream, W_e, hiB, loB);
    hipLaunchKernelGGL(fused_kernel, dim3(NB * NA), dim3(256), 0, stream,
                       A, h, E, W_h, b_h, b_e, W_ih, b_ih, W_hh, b_hh, hiB, loB, out);
}

// Round 7
// 129.326 us; speedup vs baseline: 1.0479x; 1.0479x over previous
//
#include <hip/hip_runtime.h>
#include <stdint.h>

#define NB 32
#define NA 48
#define HIN 64
#define EIN 32
#define HH 64
#define HG 16
#define NCELLS 5
#define GH 1024        // HG*HH
#define EROW 40        // shorts per staged E row (32 + 8 pad; 80 B, 16B-aligned rows)
#define WPAD 193       // LDS row stride for transposed gate weights (193%32==1 -> conflict-free)

typedef __attribute__((ext_vector_type(8))) short short8;   // 8 x bf16 (4 VGPRs)
typedef __attribute__((ext_vector_type(4))) float float4v;  // 4 x f32

__device__ __forceinline__ unsigned short f2bf(float f) {
    union { float f; unsigned int u; } v; v.f = f;
    unsigned int u = v.u + 0x7FFF + ((v.u >> 16) & 1);      // round-to-nearest-even
    return (unsigned short)(u >> 16);
}
__device__ __forceinline__ float bf2f(unsigned short s) {
    union { unsigned int u; float f; } v; v.u = ((unsigned int)s) << 16;
    return v.f;
}

// One-shot: W_e [32,1024] fp32 -> split bf16 (hi + lo) in MFMA B-fragment layout.
// slot o = ct*512 + l*8 + jj holds W_e[(l>>4)*8 + jj][ct*16 + (l&15)]
__global__ __launch_bounds__(256) void swizzle_We(const float* __restrict__ W_e,
                                                  unsigned short* __restrict__ hiB,
                                                  unsigned short* __restrict__ loB) {
    const int o  = blockIdx.x * 256 + threadIdx.x;   // 0..32767
    const int ct = o >> 9;
    const int l  = (o >> 3) & 63;
    const int jj = o & 7;
    const int k  = (l >> 4) * 8 + jj;
    const int c  = ct * 16 + (l & 15);
    const float x = W_e[k * GH + c];
    const unsigned short hb = f2bf(x);
    hiB[o] = hb;
    loB[o] = f2bf(x - bf2f(hb));
}

// Edge phase specialized on compile-time tile count NT (0..3): every fragment/
// mask array constant-indexed -> register-resident.
template <int NT>
__device__ __forceinline__ void edge_phase(
    const unsigned short* __restrict__ hiB, const unsigned short* __restrict__ loB,
    const float* __restrict__ b_e,
    const unsigned short* EcolH, const unsigned short* EcolL,
    const int* ilist, int cnt, int wave, int lane, int mrow, int quad,
    float* Esum_s)
{
    const float4v zero4 = {0.0f, 0.0f, 0.0f, 0.0f};
    short8 aH[NT ? NT : 1], aL[NT ? NT : 1];
    float4v mk[NT ? NT : 1];
    #pragma unroll
    for (int rt = 0; rt < NT; ++rt) {
        const int i = ilist[16 * rt + mrow];
        aH[rt] = *(const short8*)(&EcolH[i * EROW + quad * 8]);
        aL[rt] = *(const short8*)(&EcolL[i * EROW + quad * 8]);
        #pragma unroll
        for (int rg = 0; rg < 4; ++rg)
            mk[rt][rg] = (16 * rt + quad * 4 + rg < cnt) ? 1.0f : 0.0f;
    }
    float be[16];
    #pragma unroll
    for (int t = 0; t < 16; ++t)
        be[t] = b_e[(wave * 16 + t) * 16 + mrow];

    #pragma unroll 4
    for (int t = 0; t < 16; ++t) {
        const int ct = wave * 16 + t;
        const short8 bfH = *(const short8*)(hiB + (size_t)ct * 512 + lane * 8);
        const short8 bfL = *(const short8*)(loB + (size_t)ct * 512 + lane * 8);
        float psum = 0.0f;
        #pragma unroll
        for (int rt = 0; rt < NT; ++rt) {
            // split-bf16 product: A_lo*B_hi + A_hi*B_lo + A_hi*B_hi (fp32 acc)
            float4v d = __builtin_amdgcn_mfma_f32_16x16x32_bf16(aL[rt], bfH, zero4, 0, 0, 0);
            d = __builtin_amdgcn_mfma_f32_16x16x32_bf16(aH[rt], bfL, d, 0, 0, 0);
            d = __builtin_amdgcn_mfma_f32_16x16x32_bf16(aH[rt], bfH, d, 0, 0, 0);
            #pragma unroll
            for (int rg = 0; rg < 4; ++rg)
                psum = fmaf(fmaxf(d[rg] + be[t], 0.0f), mk[rt][rg], psum);
        }
        psum += __shfl_xor(psum, 16);
        psum += __shfl_xor(psum, 32);
        if (lane < 16) {
            const int c = ct * 16 + lane;
            Esum_s[(c >> 6) * 68 + (c & 63)] = psum;
        }
    }
}

// One block per node (b,j), 256 threads / 4 waves.
// Gate weights live in LDS (transposed, pad WPAD): round 5/6 showed the
// compiler will NOT keep 80-float register arrays live across the NCELLS loop
// (VGPR stayed 68 even with a 256 cap) - it re-sank the global loads, and the
// per-lane stride-256B reloads cost ~64 cache lines per wave-load, ~45us.
__global__ __launch_bounds__(256, 2) void fused_kernel(
    const float* __restrict__ A,  const float* __restrict__ h,
    const float* __restrict__ E,
    const float* __restrict__ W_h, const float* __restrict__ b_h,
    const float* __restrict__ b_e,
    const float* __restrict__ W_ih, const float* __restrict__ b_ih,
    const float* __restrict__ W_hh, const float* __restrict__ b_hh,
    const unsigned short* __restrict__ hiB, const unsigned short* __restrict__ loB,
    float* __restrict__ out)
{
    __shared__ unsigned short EcolH[NA * EROW];  // E[b,:,j,:] bf16 hi
    __shared__ unsigned short EcolL[NA * EROW];  // bf16 lo (residual)
    __shared__ float Esum_s[16 * 68];            // padded stride 68 (conflict-free)
    __shared__ float wihT_s[HG * WPAD];          // wihT[g*193 + c] = W_ih[c][g]
    __shared__ float whhT_s[HH * WPAD];          // whhT[k*193 + c] = W_hh[c][k]
    __shared__ int   ilist[NA];
    __shared__ int   cnt_s;
    __shared__ float hc_s[HH];
    __shared__ float M_s[HG];
    __shared__ float gsum_s[2 * HH];
    __shared__ float gin_s[HH], ghn_s[HH];

    const int node = blockIdx.x;                // b*48 + j
    const int b = node / NA, j = node - b * NA;
    const int tid = threadIdx.x, lane = tid & 63, wave = tid >> 6;
    const int mrow = lane & 15, quad = lane >> 4;

    // ---- stage E[b,:,j,:] -> split bf16 LDS (coalesced float4 per 8 threads/row) ----
    for (int idx = tid; idx < NA * 8; idx += 256) {
        const int r = idx >> 3, q = idx & 7;
        const float4 ev = *(const float4*)(E + ((size_t)(b * NA + r) * NA + j) * EIN + 4 * q);
        unsigned short h0 = f2bf(ev.x), h1 = f2bf(ev.y), h2 = f2bf(ev.z), h3 = f2bf(ev.w);
        unsigned short l0 = f2bf(ev.x - bf2f(h0)), l1 = f2bf(ev.y - bf2f(h1));
        unsigned short l2 = f2bf(ev.z - bf2f(h2)), l3 = f2bf(ev.w - bf2f(h3));
        *(uint2*)(&EcolH[r * EROW + 4 * q]) =
            make_uint2((unsigned int)h0 | ((unsigned int)h1 << 16),
                       (unsigned int)h2 | ((unsigned int)h3 << 16));
        *(uint2*)(&EcolL[r * EROW + 4 * q]) =
            make_uint2((unsigned int)l0 | ((unsigned int)l1 << 16),
                       (unsigned int)l2 | ((unsigned int)l3 << 16));
    }
    // ---- stage gate weights -> LDS transposed (coalesced reads, pad-193 writes) ----
    #pragma unroll
    for (int i = 0; i < 3; ++i) {               // W_ih: 3072 floats = 768 float4
        const int idx4 = tid + i * 256;
        const float4 v = *(const float4*)(W_ih + idx4 * 4);
        const int c = idx4 >> 2, g0 = (idx4 & 3) * 4;
        wihT_s[(g0 + 0) * WPAD + c] = v.x;
        wihT_s[(g0 + 1) * WPAD + c] = v.y;
        wihT_s[(g0 + 2) * WPAD + c] = v.z;
        wihT_s[(g0 + 3) * WPAD + c] = v.w;
    }
    #pragma unroll
    for (int i = 0; i < 12; ++i) {              // W_hh: 12288 floats = 3072 float4
        const int idx4 = tid + i * 256;
        const float4 v = *(const float4*)(W_hh + idx4 * 4);
        const int c = idx4 >> 4, k0 = (idx4 & 15) * 4;
        whhT_s[(k0 + 0) * WPAD + c] = v.x;
        whhT_s[(k0 + 1) * WPAD + c] = v.y;
        whhT_s[(k0 + 2) * WPAD + c] = v.z;
        whhT_s[(k0 + 3) * WPAD + c] = v.w;
    }
    // ---- compacted active-row list from column j of A (entries exactly 0/1) ----
    if (tid < 64) {
        if (tid < NA) ilist[tid] = 0;
        const float a = (tid < NA) ? A[((size_t)b * NA + tid) * NA + j] : 0.0f;
        const unsigned long long m = __ballot(a != 0.0f);
        if (a != 0.0f) ilist[__popcll(m & ((1ull << tid) - 1ull))] = tid;
        if (tid == 0) cnt_s = (int)__popcll(m);
    }
    __syncthreads();

    const int cnt = cnt_s;   // block-uniform -> scalar branches below
    if (cnt == 0)
        edge_phase<0>(hiB, loB, b_e, EcolH, EcolL, ilist, cnt, wave, lane, mrow, quad, Esum_s);
    else if (cnt <= 16)
        edge_phase<1>(hiB, loB, b_e, EcolH, EcolL, ilist, cnt, wave, lane, mrow, quad, Esum_s);
    else if (cnt <= 32)
        edge_phase<2>(hiB, loB, b_e, EcolH, EcolL, ilist, cnt, wave, lane, mrow, quad, Esum_s);
    else
        edge_phase<3>(hiB, loB, b_e, EcolH, EcolL, ilist, cnt, wave, lane, mrow, quad, Esum_s);

    // biases: two scalars per gate thread (cheap to keep in registers)
    float bihc = 0.0f, bhhc = 0.0f;
    if (tid < 3 * HH) { bihc = b_ih[tid]; bhhc = b_hh[tid]; }

    // hv = relu(h @ W_h + b_h) * maskh  (wave 0; maskh from ROW j of A)
    if (tid < HH) {
        const float a = (lane < NA) ? A[(size_t)node * NA + lane] : 0.0f;
        const unsigned long long mrowm = __ballot(a != 0.0f);
        const float maskh = (mrowm != 0ull) ? 1.0f : 0.0f;
        const float hr = h[(size_t)node * HIN + lane];
        float acc = b_h[lane];
        #pragma unroll
        for (int k = 0; k < HIN; ++k)
            acc = fmaf(__shfl(hr, k), W_h[k * HH + lane], acc);
        hc_s[lane] = fmaxf(acc, 0.0f) * maskh;
    }
    __syncthreads();

    // ---- phase 2: 5 GRUCell iterations ----
    const float* wihT_t = wihT_s + tid;   // per-thread column base
    const float* whhT_t = whhT_s + tid;
    #pragma unroll 1
    for (int it = 0; it < NCELLS; ++it) {
        {   // M[g] = Esum[g,:] . hc  -- all 256 threads, stride-68 (conflict-free)
            const int g = tid >> 4, q = tid & 15;
            const float4v e4 = *(const float4v*)(Esum_s + g * 68 + 4 * q);
            const float4v h4 = *(const float4v*)(hc_s + 4 * q);
            float p = e4[0] * h4[0];
            p = fmaf(e4[1], h4[1], p);
            p = fmaf(e4[2], h4[2], p);
            p = fmaf(e4[3], h4[3], p);
            p += __shfl_xor(p, 1);
            p += __shfl_xor(p, 2);
            p += __shfl_xor(p, 4);
            p += __shfl_xor(p, 8);
            if (q == 0) M_s[g] = p;
        }
        __syncthreads();
        if (tid < 3 * HH) {   // gate pre-activations; weights from LDS (conflict-free)
            const float4v m0 = *(const float4v*)(M_s);
            const float4v m1 = *(const float4v*)(M_s + 4);
            const float4v m2 = *(const float4v*)(M_s + 8);
            const float4v m3 = *(const float4v*)(M_s + 12);
            float gi0 = bihc, gi1 = 0.0f;
            gi0 = fmaf(m0[0], wihT_t[ 0 * WPAD], gi0); gi1 = fmaf(m0[1], wihT_t[ 1 * WPAD], gi1);
            gi0 = fmaf(m0[2], wihT_t[ 2 * WPAD], gi0); gi1 = fmaf(m0[3], wihT_t[ 3 * WPAD], gi1);
            gi0 = fmaf(m1[0], wihT_t[ 4 * WPAD], gi0); gi1 = fmaf(m1[1], wihT_t[ 5 * WPAD], gi1);
            gi0 = fmaf(m1[2], wihT_t[ 6 * WPAD], gi0); gi1 = fmaf(m1[3], wihT_t[ 7 * WPAD], gi1);
            gi0 = fmaf(m2[0], wihT_t[ 8 * WPAD], gi0); gi1 = fmaf(m2[1], wihT_t[ 9 * WPAD], gi1);
            gi0 = fmaf(m2[2], wihT_t[10 * WPAD], gi0); gi1 = fmaf(m2[3], wihT_t[11 * WPAD], gi1);
            gi0 = fmaf(m3[0], wihT_t[12 * WPAD], gi0); gi1 = fmaf(m3[1], wihT_t[13 * WPAD], gi1);
            gi0 = fmaf(m3[2], wihT_t[14 * WPAD], gi0); gi1 = fmaf(m3[3], wihT_t[15 * WPAD], gi1);

            float gh0 = bhhc, gh1 = 0.0f, gh2 = 0.0f, gh3 = 0.0f;
            #pragma unroll
            for (int k = 0; k < HH; k += 4) {
                const float4v h4 = *(const float4v*)(hc_s + k);   // b128 broadcast
                gh0 = fmaf(h4[0], whhT_t[(k + 0) * WPAD], gh0);
                gh1 = fmaf(h4[1], whhT_t[(k + 1) * WPAD], gh1);
                gh2 = fmaf(h4[2], whhT_t[(k + 2) * WPAD], gh2);
                gh3 = fmaf(h4[3], whhT_t[(k + 3) * WPAD], gh3);
            }
            const float gi = gi0 + gi1;
            const float gh = (gh0 + gh1) + (gh2 + gh3);
            if (tid < 2 * HH) gsum_s[tid] = gi + gh;            // r,z need only the sum
            else { gin_s[tid - 2 * HH] = gi; ghn_s[tid - 2 * HH] = gh; }
        }
        __syncthreads();
        if (tid < HH) {
            const float r = 1.0f / (1.0f + __expf(-gsum_s[tid]));
            const float z = 1.0f / (1.0f + __expf(-gsum_s[HH + tid]));
            const float nin = gin_s[tid] + r * ghn_s[tid];
            const float n = 1.0f - 2.0f / (__expf(2.0f * nin) + 1.0f);  // tanh
            hc_s[tid] = (1.0f - z) * n + z * hc_s[tid];
        }
        __syncthreads();
    }

    if (tid < HH) out[(size_t)node * HH + tid] = hc_s[tid];
}

extern "C" void kernel_launch(void* const* d_in, const int* in_sizes, int n_in,
                              void* d_out, int out_size, void* d_ws, size_t ws_size,
                              hipStream_t stream) {
    const float* A    = (const float*)d_in[0];
    const float* h    = (const float*)d_in[1];
    const float* E    = (const float*)d_in[2];
    const float* W_h  = (const float*)d_in[3];
    const float* b_h  = (const float*)d_in[4];
    const float* W_e  = (const float*)d_in[5];
    const float* b_e  = (const float*)d_in[6];
    const float* W_ih = (const float*)d_in[7];
    const float* b_ih = (const float*)d_in[8];
    const float* W_hh = (const float*)d_in[9];
    const float* b_hh = (const float*)d_in[10];
    unsigned short* hiB = (unsigned short*)d_ws;            // 64 KB
    unsigned short* loB = hiB + 32768;                      // 64 KB
    float* out = (float*)d_out;

    hipLaunchKernelGGL(swizzle_We, dim3(128), dim3(256), 0, stream, W_e, hiB, loB);
    hipLaunchKernelGGL(fused_kernel, dim3(NB * NA), dim3(256), 0, stream,
                       A, h, E, W_h, b_h, b_e, W_ih, b_ih, W_hh, b_hh, hiB, loB, out);
}

// Round 8
// 121.128 us; speedup vs baseline: 1.1188x; 1.0677x over previous
//
#include <hip/hip_runtime.h>
#include <stdint.h>

#define NB 32
#define NA 48
#define HIN 64
#define EIN 32
#define HH 64
#define HG 16
#define NCELLS 5
#define GH 1024        // HG*HH
#define EROW 40        // shorts per staged E row (32 + 8 pad; 80 B, 16B-aligned rows)

typedef __attribute__((ext_vector_type(8))) short short8;   // 8 x bf16 (4 VGPRs)
typedef __attribute__((ext_vector_type(4))) float float4v;  // 4 x f32

__device__ __forceinline__ unsigned short f2bf(float f) {
    union { float f; unsigned int u; } v; v.f = f;
    unsigned int u = v.u + 0x7FFF + ((v.u >> 16) & 1);      // round-to-nearest-even
    return (unsigned short)(u >> 16);
}
__device__ __forceinline__ float bf2f(unsigned short s) {
    union { unsigned int u; float f; } v; v.u = ((unsigned int)s) << 16;
    return v.f;
}

// One-shot: W_e [32,1024] fp32 -> split bf16 (hi + lo) in MFMA B-fragment layout.
// slot o = ct*512 + l*8 + jj holds W_e[(l>>4)*8 + jj][ct*16 + (l&15)]
__global__ __launch_bounds__(256) void swizzle_We(const float* __restrict__ W_e,
                                                  unsigned short* __restrict__ hiB,
                                                  unsigned short* __restrict__ loB) {
    const int o  = blockIdx.x * 256 + threadIdx.x;   // 0..32767
    const int ct = o >> 9;
    const int l  = (o >> 3) & 63;
    const int jj = o & 7;
    const int k  = (l >> 4) * 8 + jj;
    const int c  = ct * 16 + (l & 15);
    const float x = W_e[k * GH + c];
    const unsigned short hb = f2bf(x);
    hiB[o] = hb;
    loB[o] = f2bf(x - bf2f(hb));
}

// One-shot: gate weights -> chunk-major fp32 float4 workspace.
// gw4[j*192 + c] = (j<4) ? W_ih[c][4j..4j+3] : W_hh[c][4(j-4)..4(j-4)+3]
// Gate-loop reads become lane-consecutive 16B -> one 1KB wave transaction, L2-hot.
__global__ __launch_bounds__(256) void prep_gw(const float* __restrict__ W_ih,
                                               const float* __restrict__ W_hh,
                                               float4* __restrict__ gw4) {
    const int idx = blockIdx.x * 256 + threadIdx.x;  // 0..3839
    if (idx >= 20 * 192) return;
    const int j = idx / 192;
    const int c = idx - j * 192;
    float4 v;
    if (j < 4)  v = *(const float4*)(W_ih + c * HG + 4 * j);
    else        v = *(const float4*)(W_hh + c * HH + 4 * (j - 4));
    gw4[idx] = v;
}

// Edge phase specialized on compile-time tile count NT (0..3): every fragment/
// mask array constant-indexed -> register-resident.
template <int NT>
__device__ __forceinline__ void edge_phase(
    const unsigned short* __restrict__ hiB, const unsigned short* __restrict__ loB,
    const float* __restrict__ b_e,
    const unsigned short* EcolH, const unsigned short* EcolL,
    const int* ilist, int cnt, int wave, int lane, int mrow, int quad,
    float* Esum_s)
{
    const float4v zero4 = {0.0f, 0.0f, 0.0f, 0.0f};
    short8 aH[NT ? NT : 1], aL[NT ? NT : 1];
    float4v mk[NT ? NT : 1];
    #pragma unroll
    for (int rt = 0; rt < NT; ++rt) {
        const int i = ilist[16 * rt + mrow];
        aH[rt] = *(const short8*)(&EcolH[i * EROW + quad * 8]);
        aL[rt] = *(const short8*)(&EcolL[i * EROW + quad * 8]);
        #pragma unroll
        for (int rg = 0; rg < 4; ++rg)
            mk[rt][rg] = (16 * rt + quad * 4 + rg < cnt) ? 1.0f : 0.0f;
    }
    #pragma unroll 4
    for (int t = 0; t < 16; ++t) {
        const int ct = wave * 16 + t;
        const short8 bfH = *(const short8*)(hiB + (size_t)ct * 512 + lane * 8);
        const short8 bfL = *(const short8*)(loB + (size_t)ct * 512 + lane * 8);
        const float be = b_e[ct * 16 + mrow];
        float psum = 0.0f;
        #pragma unroll
        for (int rt = 0; rt < NT; ++rt) {
            // split-bf16 product: A_lo*B_hi + A_hi*B_lo + A_hi*B_hi (fp32 acc)
            float4v d = __builtin_amdgcn_mfma_f32_16x16x32_bf16(aL[rt], bfH, zero4, 0, 0, 0);
            d = __builtin_amdgcn_mfma_f32_16x16x32_bf16(aH[rt], bfL, d, 0, 0, 0);
            d = __builtin_amdgcn_mfma_f32_16x16x32_bf16(aH[rt], bfH, d, 0, 0, 0);
            #pragma unroll
            for (int rg = 0; rg < 4; ++rg)
                psum = fmaf(fmaxf(d[rg] + be, 0.0f), mk[rt][rg], psum);
        }
        psum += __shfl_xor(psum, 16);
        psum += __shfl_xor(psum, 32);
        if (lane < 16) {
            const int c = ct * 16 + lane;
            Esum_s[(c >> 6) * 68 + (c & 63)] = psum;
        }
    }
}

// One block per node (b,j), 256 threads / 4 waves.
// LDS kept small (~13.5 KB) so 4 blocks/CU reside (R7's 75 KB LDS capped us at
// 2 blocks/CU -> 3 serial rounds, occupancy 19%, 53 us). Gate weights stream
// from the chunk-major gw4 workspace: coalesced 16B/lane, L2-resident.
__global__ __launch_bounds__(256, 4) void fused_kernel(
    const float* __restrict__ A,  const float* __restrict__ h,
    const float* __restrict__ E,
    const float* __restrict__ W_h, const float* __restrict__ b_h,
    const float* __restrict__ b_e,
    const float* __restrict__ b_ih, const float* __restrict__ b_hh,
    const unsigned short* __restrict__ hiB, const unsigned short* __restrict__ loB,
    const float4* __restrict__ gw4,
    float* __restrict__ out)
{
    __shared__ unsigned short EcolH[NA * EROW];  // E[b,:,j,:] bf16 hi
    __shared__ unsigned short EcolL[NA * EROW];  // bf16 lo (residual)
    __shared__ float Esum_s[16 * 68];            // padded stride 68
    __shared__ int   ilist[NA];
    __shared__ int   cnt_s;
    __shared__ float hc_s[HH];
    __shared__ float M_s[HG];
    __shared__ float gsum_s[2 * HH];
    __shared__ float gin_s[HH], ghn_s[HH];

    const int node = blockIdx.x;                // b*48 + j
    const int b = node / NA, j = node - b * NA;
    const int tid = threadIdx.x, lane = tid & 63, wave = tid >> 6;
    const int mrow = lane & 15, quad = lane >> 4;

    // ---- stage E[b,:,j,:] -> split bf16 LDS (coalesced float4 per 8 threads/row) ----
    for (int idx = tid; idx < NA * 8; idx += 256) {
        const int r = idx >> 3, q = idx & 7;
        const float4 ev = *(const float4*)(E + ((size_t)(b * NA + r) * NA + j) * EIN + 4 * q);
        unsigned short h0 = f2bf(ev.x), h1 = f2bf(ev.y), h2 = f2bf(ev.z), h3 = f2bf(ev.w);
        unsigned short l0 = f2bf(ev.x - bf2f(h0)), l1 = f2bf(ev.y - bf2f(h1));
        unsigned short l2 = f2bf(ev.z - bf2f(h2)), l3 = f2bf(ev.w - bf2f(h3));
        *(uint2*)(&EcolH[r * EROW + 4 * q]) =
            make_uint2((unsigned int)h0 | ((unsigned int)h1 << 16),
                       (unsigned int)h2 | ((unsigned int)h3 << 16));
        *(uint2*)(&EcolL[r * EROW + 4 * q]) =
            make_uint2((unsigned int)l0 | ((unsigned int)l1 << 16),
                       (unsigned int)l2 | ((unsigned int)l3 << 16));
    }
    // ---- compacted active-row list from column j of A (entries exactly 0/1) ----
    if (tid < 64) {
        if (tid < NA) ilist[tid] = 0;
        const float a = (tid < NA) ? A[((size_t)b * NA + tid) * NA + j] : 0.0f;
        const unsigned long long m = __ballot(a != 0.0f);
        if (a != 0.0f) ilist[__popcll(m & ((1ull << tid) - 1ull))] = tid;
        if (tid == 0) cnt_s = (int)__popcll(m);
    }
    __syncthreads();

    const int cnt = cnt_s;   // block-uniform -> scalar branches below
    if (cnt == 0)
        edge_phase<0>(hiB, loB, b_e, EcolH, EcolL, ilist, cnt, wave, lane, mrow, quad, Esum_s);
    else if (cnt <= 16)
        edge_phase<1>(hiB, loB, b_e, EcolH, EcolL, ilist, cnt, wave, lane, mrow, quad, Esum_s);
    else if (cnt <= 32)
        edge_phase<2>(hiB, loB, b_e, EcolH, EcolL, ilist, cnt, wave, lane, mrow, quad, Esum_s);
    else
        edge_phase<3>(hiB, loB, b_e, EcolH, EcolL, ilist, cnt, wave, lane, mrow, quad, Esum_s);

    // gate biases (two scalars per gate thread)
    float bihc = 0.0f, bhhc = 0.0f;
    if (tid < 3 * HH) { bihc = b_ih[tid]; bhhc = b_hh[tid]; }

    // hv = relu(h @ W_h + b_h) * maskh  (wave 0; maskh from ROW j of A)
    if (tid < HH) {
        const float a = (lane < NA) ? A[(size_t)node * NA + lane] : 0.0f;
        const unsigned long long mrowm = __ballot(a != 0.0f);
        const float maskh = (mrowm != 0ull) ? 1.0f : 0.0f;
        const float hr = h[(size_t)node * HIN + lane];
        float acc = b_h[lane];
        #pragma unroll
        for (int k = 0; k < HIN; ++k)
            acc = fmaf(__shfl(hr, k), W_h[k * HH + lane], acc);
        hc_s[lane] = fmaxf(acc, 0.0f) * maskh;
    }
    __syncthreads();

    // ---- phase 2: 5 GRUCell iterations; weights streamed from gw4 (L2-hot) ----
    #pragma unroll 1
    for (int it = 0; it < NCELLS; ++it) {
        {   // M[g] = Esum[g,:] . hc  -- all 256 threads
            const int g = tid >> 4, q = tid & 15;
            const float4v e4 = *(const float4v*)(Esum_s + g * 68 + 4 * q);
            const float4v h4 = *(const float4v*)(hc_s + 4 * q);
            float p = e4[0] * h4[0];
            p = fmaf(e4[1], h4[1], p);
            p = fmaf(e4[2], h4[2], p);
            p = fmaf(e4[3], h4[3], p);
            p += __shfl_xor(p, 1);
            p += __shfl_xor(p, 2);
            p += __shfl_xor(p, 4);
            p += __shfl_xor(p, 8);
            if (q == 0) M_s[g] = p;
        }
        __syncthreads();
        if (tid < 3 * HH) {   // gate pre-activations; gw4 coalesced, M/hc broadcast
            const float4* gp = gw4 + tid;
            float gi0 = bihc, gi1 = 0.0f;
            #pragma unroll
            for (int jj = 0; jj < 4; jj += 2) {
                const float4 w0 = gp[jj * 192];
                const float4 w1 = gp[(jj + 1) * 192];
                const float4v m0 = *(const float4v*)(M_s + 4 * jj);
                const float4v m1 = *(const float4v*)(M_s + 4 * jj + 4);
                gi0 = fmaf(m0[0], w0.x, gi0); gi1 = fmaf(m0[1], w0.y, gi1);
                gi0 = fmaf(m0[2], w0.z, gi0); gi1 = fmaf(m0[3], w0.w, gi1);
                gi0 = fmaf(m1[0], w1.x, gi0); gi1 = fmaf(m1[1], w1.y, gi1);
                gi0 = fmaf(m1[2], w1.z, gi0); gi1 = fmaf(m1[3], w1.w, gi1);
            }
            float gh0 = bhhc, gh1 = 0.0f, gh2 = 0.0f, gh3 = 0.0f;
            #pragma unroll
            for (int jj = 4; jj < 20; jj += 2) {
                const float4 w0 = gp[jj * 192];
                const float4 w1 = gp[(jj + 1) * 192];
                const float4v h0 = *(const float4v*)(hc_s + 4 * (jj - 4));
                const float4v h1 = *(const float4v*)(hc_s + 4 * (jj - 4) + 4);
                gh0 = fmaf(h0[0], w0.x, gh0); gh1 = fmaf(h0[1], w0.y, gh1);
                gh2 = fmaf(h0[2], w0.z, gh2); gh3 = fmaf(h0[3], w0.w, gh3);
                gh0 = fmaf(h1[0], w1.x, gh0); gh1 = fmaf(h1[1], w1.y, gh1);
                gh2 = fmaf(h1[2], w1.z, gh2); gh3 = fmaf(h1[3], w1.w, gh3);
            }
            const float gi = gi0 + gi1;
            const float gh = (gh0 + gh1) + (gh2 + gh3);
            if (tid < 2 * HH) gsum_s[tid] = gi + gh;            // r,z need only the sum
            else { gin_s[tid - 2 * HH] = gi; ghn_s[tid - 2 * HH] = gh; }
        }
        __syncthreads();
        if (tid < HH) {
            const float r = 1.0f / (1.0f + __expf(-gsum_s[tid]));
            const float z = 1.0f / (1.0f + __expf(-gsum_s[HH + tid]));
            const float nin = gin_s[tid] + r * ghn_s[tid];
            const float n = 1.0f - 2.0f / (__expf(2.0f * nin) + 1.0f);  // tanh
            hc_s[tid] = (1.0f - z) * n + z * hc_s[tid];
        }
        __syncthreads();
    }

    if (tid < HH) out[(size_t)node * HH + tid] = hc_s[tid];
}

extern "C" void kernel_launch(void* const* d_in, const int* in_sizes, int n_in,
                              void* d_out, int out_size, void* d_ws, size_t ws_size,
                              hipStream_t stream) {
    const float* A    = (const float*)d_in[0];
    const float* h    = (const float*)d_in[1];
    const float* E    = (const float*)d_in[2];
    const float* W_h  = (const float*)d_in[3];
    const float* b_h  = (const float*)d_in[4];
    const float* W_e  = (const float*)d_in[5];
    const float* b_e  = (const float*)d_in[6];
    const float* W_ih = (const float*)d_in[7];
    const float* b_ih = (const float*)d_in[8];
    const float* W_hh = (const float*)d_in[9];
    const float* b_hh = (const float*)d_in[10];
    unsigned short* hiB = (unsigned short*)d_ws;            // 64 KB
    unsigned short* loB = hiB + 32768;                      // 64 KB
    float4* gw4 = (float4*)(loB + 32768);                   // 61.4 KB (20*192 float4)
    float* out = (float*)d_out;

    hipLaunchKernelGGL(swizzle_We, dim3(128), dim3(256), 0, stream, W_e, hiB, loB);
    hipLaunchKernelGGL(prep_gw, dim3(15), dim3(256), 0, stream, W_ih, W_hh, gw4);
    hipLaunchKernelGGL(fused_kernel, dim3(NB * NA), dim3(256), 0, stream,
                       A, h, E, W_h, b_h, b_e, b_ih, b_hh, hiB, loB, gw4, out);
}

// Round 9
// 113.391 us; speedup vs baseline: 1.1951x; 1.0682x over previous
//
#include <hip/hip_runtime.h>
#include <stdint.h>

#define NB 32
#define NA 48
#define HIN 64
#define EIN 32
#define HH 64
#define HG 16
#define NCELLS 5
#define GH 1024        // HG*HH
#define EROW 40        // shorts per staged E row (32 + 8 pad; 80 B, 16B-aligned rows)
#define P3 3           // nodes per block
#define ESTR 1088      // Esum_s floats per node (16 rows x 68 padded)

typedef __attribute__((ext_vector_type(8))) short short8;   // 8 x bf16 (4 VGPRs)
typedef __attribute__((ext_vector_type(4))) float float4v;  // 4 x f32

__device__ __forceinline__ unsigned short f2bf(float f) {
    union { float f; unsigned int u; } v; v.f = f;
    unsigned int u = v.u + 0x7FFF + ((v.u >> 16) & 1);      // round-to-nearest-even
    return (unsigned short)(u >> 16);
}
__device__ __forceinline__ float bf2f(unsigned short s) {
    union { unsigned int u; float f; } v; v.u = ((unsigned int)s) << 16;
    return v.f;
}

// One-shot: W_e [32,1024] fp32 -> split bf16 (hi + lo) in MFMA B-fragment layout.
__global__ __launch_bounds__(256) void swizzle_We(const float* __restrict__ W_e,
                                                  unsigned short* __restrict__ hiB,
                                                  unsigned short* __restrict__ loB) {
    const int o  = blockIdx.x * 256 + threadIdx.x;   // 0..32767
    const int ct = o >> 9;
    const int l  = (o >> 3) & 63;
    const int jj = o & 7;
    const int k  = (l >> 4) * 8 + jj;
    const int c  = ct * 16 + (l & 15);
    const float x = W_e[k * GH + c];
    const unsigned short hb = f2bf(x);
    hiB[o] = hb;
    loB[o] = f2bf(x - bf2f(hb));
}

// One-shot: gate weights -> chunk-major fp32 float4 workspace (coalesced streams).
__global__ __launch_bounds__(256) void prep_gw(const float* __restrict__ W_ih,
                                               const float* __restrict__ W_hh,
                                               float4* __restrict__ gw4) {
    const int idx = blockIdx.x * 256 + threadIdx.x;  // 0..3839
    if (idx >= 20 * 192) return;
    const int j = idx / 192;
    const int c = idx - j * 192;
    float4 v;
    if (j < 4)  v = *(const float4*)(W_ih + c * HG + 4 * j);
    else        v = *(const float4*)(W_hh + c * HH + 4 * (j - 4));
    gw4[idx] = v;
}

// Edge phase for 3 nodes, specialized on block-uniform max tile count NTMAX.
// One bfrag load serves all 3 nodes (B traffic /3). Masks via LDS broadcast.
// All register arrays constant-indexed (p, rt fully unrolled; bias loaded
// directly per t -- no runtime-indexed register arrays, per the R4 lesson).
template <int NTMAX>
__device__ __forceinline__ void edge_phase3(
    const unsigned short* __restrict__ hiB, const unsigned short* __restrict__ loB,
    const float* __restrict__ b_e,
    const unsigned short* EcolH, const unsigned short* EcolL,   // [3][48][EROW]
    const float* mask_s,                                        // [3][3][16]
    int wave, int lane, int mrow, int quad,
    float* Esum_s)                                              // [3][ESTR]
{
    const float4v zero4 = {0.0f, 0.0f, 0.0f, 0.0f};
    short8 aH[P3][NTMAX ? NTMAX : 1], aL[P3][NTMAX ? NTMAX : 1];
    #pragma unroll
    for (int p = 0; p < P3; ++p)
        #pragma unroll
        for (int rt = 0; rt < NTMAX; ++rt) {
            const int off = (p * 48 + 16 * rt + mrow) * EROW + quad * 8;
            aH[p][rt] = *(const short8*)(EcolH + off);
            aL[p][rt] = *(const short8*)(EcolL + off);
        }

    #pragma unroll 2
    for (int t = 0; t < 16; ++t) {
        const int ct = wave * 16 + t;
        const short8 bfH = *(const short8*)(hiB + (size_t)ct * 512 + lane * 8);
        const short8 bfL = *(const short8*)(loB + (size_t)ct * 512 + lane * 8);
        const float be = b_e[ct * 16 + mrow];   // L1-hot, 16-lane broadcast
        float psum[P3] = {0.0f, 0.0f, 0.0f};
        #pragma unroll
        for (int p = 0; p < P3; ++p) {
            #pragma unroll
            for (int rt = 0; rt < NTMAX; ++rt) {
                // split-bf16: A_lo*B_hi + A_hi*B_lo + A_hi*B_hi (fp32 acc)
                float4v d = __builtin_amdgcn_mfma_f32_16x16x32_bf16(aL[p][rt], bfH, zero4, 0, 0, 0);
                d = __builtin_amdgcn_mfma_f32_16x16x32_bf16(aH[p][rt], bfL, d, 0, 0, 0);
                d = __builtin_amdgcn_mfma_f32_16x16x32_bf16(aH[p][rt], bfH, d, 0, 0, 0);
                const float4v mk = *(const float4v*)(mask_s + p * 48 + rt * 16 + quad * 4);
                #pragma unroll
                for (int rg = 0; rg < 4; ++rg)
                    psum[p] = fmaf(fmaxf(d[rg] + be, 0.0f), mk[rg], psum[p]);
            }
        }
        #pragma unroll
        for (int p = 0; p < P3; ++p) {
            float ps = psum[p];
            ps += __shfl_xor(ps, 16);
            ps += __shfl_xor(ps, 32);
            if (lane < 16) {
                const int c = ct * 16 + lane;
                Esum_s[p * ESTR + (c >> 6) * 68 + (c & 63)] = ps;
            }
        }
    }
}

// One block per 3 nodes. Grid 512 = exactly 2 blocks/CU (balanced, one round).
// Weight/B-fragment L2 traffic amortized 3x vs the R8 per-node kernel.
__global__ __launch_bounds__(256, 2) void fused_kernel(
    const float* __restrict__ A,  const float* __restrict__ h,
    const float* __restrict__ E,
    const float* __restrict__ W_h, const float* __restrict__ b_h,
    const float* __restrict__ b_e,
    const float* __restrict__ b_ih, const float* __restrict__ b_hh,
    const unsigned short* __restrict__ hiB, const unsigned short* __restrict__ loB,
    const float4* __restrict__ gw4,
    float* __restrict__ out)
{
    __shared__ unsigned short EcolH[P3 * NA * EROW];  // compacted E rows, bf16 hi
    __shared__ unsigned short EcolL[P3 * NA * EROW];  // bf16 lo (residual)
    __shared__ float Esum_s[P3 * ESTR];
    __shared__ float mask_s[P3 * 48];                 // [p][rt][ri] validity
    __shared__ int   ilist[P3 * NA];
    __shared__ int   cnt_s[P3];
    __shared__ float hc_s[P3 * HH];
    __shared__ float M_s[P3 * HG];
    __shared__ float gsum_s[P3 * 2 * HH];
    __shared__ float gin_s[P3 * HH], ghn_s[P3 * HH];

    const int node0 = blockIdx.x * P3;          // 3 nodes share batch b (48%3==0)
    const int b = node0 / NA, j0 = node0 - b * NA;
    const int tid = threadIdx.x, lane = tid & 63, wave = tid >> 6;
    const int mrow = lane & 15, quad = lane >> 4;

    // ---- ballot phase: waves 0..2 build compacted active-row lists ----
    if (wave < P3) {
        const float a = (lane < NA) ? A[((size_t)b * NA + lane) * NA + (j0 + wave)] : 0.0f;
        const unsigned long long m = __ballot(a != 0.0f);
        if (a != 0.0f) ilist[wave * NA + __popcll(m & ((1ull << lane) - 1ull))] = lane;
        if (lane == 0) cnt_s[wave] = (int)__popcll(m);
    }
    __syncthreads();

    // ---- stage compacted E rows -> split bf16 LDS; zero-pad rows >= cnt ----
    for (int idx = tid; idx < P3 * NA * 8; idx += 256) {
        const int p = idx / (NA * 8);
        const int rem = idx - p * (NA * 8);
        const int r = rem >> 3, q = rem & 7;
        uint2 hv2 = make_uint2(0u, 0u), lv2 = make_uint2(0u, 0u);
        if (r < cnt_s[p]) {
            const int i = ilist[p * NA + r];
            const float4 ev = *(const float4*)(E + ((size_t)(b * NA + i) * NA + (j0 + p)) * EIN + 4 * q);
            unsigned short h0 = f2bf(ev.x), h1 = f2bf(ev.y), h2 = f2bf(ev.z), h3 = f2bf(ev.w);
            unsigned short l0 = f2bf(ev.x - bf2f(h0)), l1 = f2bf(ev.y - bf2f(h1));
            unsigned short l2 = f2bf(ev.z - bf2f(h2)), l3 = f2bf(ev.w - bf2f(h3));
            hv2 = make_uint2((unsigned int)h0 | ((unsigned int)h1 << 16),
                             (unsigned int)h2 | ((unsigned int)h3 << 16));
            lv2 = make_uint2((unsigned int)l0 | ((unsigned int)l1 << 16),
                             (unsigned int)l2 | ((unsigned int)l3 << 16));
        }
        *(uint2*)(&EcolH[(p * NA + r) * EROW + 4 * q]) = hv2;
        *(uint2*)(&EcolL[(p * NA + r) * EROW + 4 * q]) = lv2;
    }
    // validity masks for the MFMA epilogue
    if (tid < P3 * 48) {
        const int p = tid / 48, rem = tid - p * 48;
        mask_s[tid] = (rem < cnt_s[p]) ? 1.0f : 0.0f;   // rem = rt*16+ri = global row
    }
    __syncthreads();

    const int nt0 = (cnt_s[0] + 15) >> 4, nt1 = (cnt_s[1] + 15) >> 4, nt2 = (cnt_s[2] + 15) >> 4;
    int ntmax = nt0 > nt1 ? nt0 : nt1; ntmax = ntmax > nt2 ? ntmax : nt2;   // block-uniform

    if (ntmax == 0)
        edge_phase3<0>(hiB, loB, b_e, EcolH, EcolL, mask_s, wave, lane, mrow, quad, Esum_s);
    else if (ntmax == 1)
        edge_phase3<1>(hiB, loB, b_e, EcolH, EcolL, mask_s, wave, lane, mrow, quad, Esum_s);
    else if (ntmax == 2)
        edge_phase3<2>(hiB, loB, b_e, EcolH, EcolL, mask_s, wave, lane, mrow, quad, Esum_s);
    else
        edge_phase3<3>(hiB, loB, b_e, EcolH, EcolL, mask_s, wave, lane, mrow, quad, Esum_s);

    // gate biases (shared across the 3 nodes)
    float bihc = 0.0f, bhhc = 0.0f;
    if (tid < 3 * HH) { bihc = b_ih[tid]; bhhc = b_hh[tid]; }

    // hv_p = relu(h_p @ W_h + b_h) * maskh_p  (wave p handles node p)
    if (wave < P3) {
        const int node = node0 + wave;
        const float a = (lane < NA) ? A[(size_t)node * NA + lane] : 0.0f;
        const unsigned long long mrowm = __ballot(a != 0.0f);
        const float maskh = (mrowm != 0ull) ? 1.0f : 0.0f;
        const float hr = h[(size_t)node * HIN + lane];
        float acc = b_h[lane];
        #pragma unroll
        for (int k = 0; k < HIN; ++k)
            acc = fmaf(__shfl(hr, k), W_h[k * HH + lane], acc);
        hc_s[wave * HH + lane] = fmaxf(acc, 0.0f) * maskh;
    }
    __syncthreads();

    // ---- 5 GRUCell iterations for 3 nodes; weights streamed once per iter ----
    #pragma unroll 1
    for (int it = 0; it < NCELLS; ++it) {
        if (tid < 192) {   // M[p][g] = Esum[p][g,:] . hc[p]; 4 threads per (p,g)
            const int p = tid >> 6, s = tid & 63, g = s >> 2, q = s & 3;
            const float* ep = Esum_s + p * ESTR + g * 68 + q * 16;
            const float* hp = hc_s + p * HH + q * 16;
            const float4v e0 = *(const float4v*)(ep),     h0 = *(const float4v*)(hp);
            const float4v e1 = *(const float4v*)(ep + 4), h1 = *(const float4v*)(hp + 4);
            const float4v e2 = *(const float4v*)(ep + 8), h2 = *(const float4v*)(hp + 8);
            const float4v e3 = *(const float4v*)(ep + 12), h3 = *(const float4v*)(hp + 12);
            float pp = e0[0] * h0[0];
            pp = fmaf(e0[1], h0[1], pp); pp = fmaf(e0[2], h0[2], pp); pp = fmaf(e0[3], h0[3], pp);
            pp = fmaf(e1[0], h1[0], pp); pp = fmaf(e1[1], h1[1], pp);
            pp = fmaf(e1[2], h1[2], pp); pp = fmaf(e1[3], h1[3], pp);
            pp = fmaf(e2[0], h2[0], pp); pp = fmaf(e2[1], h2[1], pp);
            pp = fmaf(e2[2], h2[2], pp); pp = fmaf(e2[3], h2[3], pp);
            pp = fmaf(e3[0], h3[0], pp); pp = fmaf(e3[1], h3[1], pp);
            pp = fmaf(e3[2], h3[2], pp); pp = fmaf(e3[3], h3[3], pp);
            pp += __shfl_xor(pp, 1);
            pp += __shfl_xor(pp, 2);
            if (q == 0) M_s[p * HG + g] = pp;
        }
        __syncthreads();
        if (tid < 192) {   // gate column c=tid for ALL 3 nodes: weights loaded once
            const float4* gp = gw4 + tid;
            float gi0 = bihc, gi1 = bihc, gi2 = bihc;
            #pragma unroll
            for (int jj = 0; jj < 4; ++jj) {
                const float4 w = gp[jj * 192];
                const float4v m0 = *(const float4v*)(M_s + 0 * HG + 4 * jj);
                const float4v m1 = *(const float4v*)(M_s + 1 * HG + 4 * jj);
                const float4v m2 = *(const float4v*)(M_s + 2 * HG + 4 * jj);
                gi0 = fmaf(m0[0], w.x, gi0); gi0 = fmaf(m0[1], w.y, gi0);
                gi0 = fmaf(m0[2], w.z, gi0); gi0 = fmaf(m0[3], w.w, gi0);
                gi1 = fmaf(m1[0], w.x, gi1); gi1 = fmaf(m1[1], w.y, gi1);
                gi1 = fmaf(m1[2], w.z, gi1); gi1 = fmaf(m1[3], w.w, gi1);
                gi2 = fmaf(m2[0], w.x, gi2); gi2 = fmaf(m2[1], w.y, gi2);
                gi2 = fmaf(m2[2], w.z, gi2); gi2 = fmaf(m2[3], w.w, gi2);
            }
            float gh0 = bhhc, gh1 = bhhc, gh2 = bhhc;
            #pragma unroll
            for (int jj = 4; jj < 20; ++jj) {
                const float4 w = gp[jj * 192];
                const float4v h0 = *(const float4v*)(hc_s + 0 * HH + 4 * (jj - 4));
                const float4v h1 = *(const float4v*)(hc_s + 1 * HH + 4 * (jj - 4));
                const float4v h2 = *(const float4v*)(hc_s + 2 * HH + 4 * (jj - 4));
                gh0 = fmaf(h0[0], w.x, gh0); gh0 = fmaf(h0[1], w.y, gh0);
                gh0 = fmaf(h0[2], w.z, gh0); gh0 = fmaf(h0[3], w.w, gh0);
                gh1 = fmaf(h1[0], w.x, gh1); gh1 = fmaf(h1[1], w.y, gh1);
                gh1 = fmaf(h1[2], w.z, gh1); gh1 = fmaf(h1[3], w.w, gh1);
                gh2 = fmaf(h2[0], w.x, gh2); gh2 = fmaf(h2[1], w.y, gh2);
                gh2 = fmaf(h2[2], w.z, gh2); gh2 = fmaf(h2[3], w.w, gh2);
            }
            if (tid < 2 * HH) {          // r,z need only the sum
                gsum_s[0 * 2 * HH + tid] = gi0 + gh0;
                gsum_s[1 * 2 * HH + tid] = gi1 + gh1;
                gsum_s[2 * 2 * HH + tid] = gi2 + gh2;
            } else {
                const int c = tid - 2 * HH;
                gin_s[0 * HH + c] = gi0; ghn_s[0 * HH + c] = gh0;
                gin_s[1 * HH + c] = gi1; ghn_s[1 * HH + c] = gh1;
                gin_s[2 * HH + c] = gi2; ghn_s[2 * HH + c] = gh2;
            }
        }
        __syncthreads();
        if (tid < 192) {   // update: thread (p,c)
            const int p = tid >> 6, c = tid & 63;
            const float r = 1.0f / (1.0f + __expf(-gsum_s[p * 2 * HH + c]));
            const float z = 1.0f / (1.0f + __expf(-gsum_s[p * 2 * HH + HH + c]));
            const float nin = gin_s[p * HH + c] + r * ghn_s[p * HH + c];
            const float n = 1.0f - 2.0f / (__expf(2.0f * nin) + 1.0f);  // tanh
            hc_s[p * HH + c] = (1.0f - z) * n + z * hc_s[p * HH + c];
        }
        __syncthreads();
    }

    if (tid < 192) out[(size_t)node0 * HH + tid] = hc_s[tid];
}

extern "C" void kernel_launch(void* const* d_in, const int* in_sizes, int n_in,
                              void* d_out, int out_size, void* d_ws, size_t ws_size,
                              hipStream_t stream) {
    const float* A    = (const float*)d_in[0];
    const float* h    = (const float*)d_in[1];
    const float* E    = (const float*)d_in[2];
    const float* W_h  = (const float*)d_in[3];
    const float* b_h  = (const float*)d_in[4];
    const float* W_e  = (const float*)d_in[5];
    const float* b_e  = (const float*)d_in[6];
    const float* W_ih = (const float*)d_in[7];
    const float* b_ih = (const float*)d_in[8];
    const float* W_hh = (const float*)d_in[9];
    const float* b_hh = (const float*)d_in[10];
    unsigned short* hiB = (unsigned short*)d_ws;            // 64 KB
    unsigned short* loB = hiB + 32768;                      // 64 KB
    float4* gw4 = (float4*)(loB + 32768);                   // 61.4 KB
    float* out = (float*)d_out;

    hipLaunchKernelGGL(swizzle_We, dim3(128), dim3(256), 0, stream, W_e, hiB, loB);
    hipLaunchKernelGGL(prep_gw, dim3(15), dim3(256), 0, stream, W_ih, W_hh, gw4);
    hipLaunchKernelGGL(fused_kernel, dim3(NB * NA / P3), dim3(256), 0, stream,
                       A, h, E, W_h, b_h, b_e, b_ih, b_hh, hiB, loB, gw4, out);
}